// Round 9
// baseline (399.579 us; speedup 1.0000x reference)
//
#include <hip/hip_runtime.h>
#include <hip/hip_bf16.h>
#include <stdint.h>

// Problem constants
#define BB   8192   // batch
#define DD   8      // features
#define PP   10     // poly basis width
#define RR   512    // TT rank
#define OUTD 64     // output dim
#define KK   5120   // expanded K = PP*RR

typedef __bf16 bf16x8 __attribute__((ext_vector_type(8)));
typedef float  f32x4  __attribute__((ext_vector_type(4)));

// ---------------------------------------------------------------------------
// frag_pack<N>: tanh + pack G(i,j,n) = G[i*ldi + j*N + n] into MFMA
// B-fragment-linear layout: dst[(j*16+kc)*32N + nt*512 + lane*8 + e]
//   n = nt*16 + (lane&15), i = kc*32 + (lane>>4)*8 + e
// ---------------------------------------------------------------------------
template <int N>
__global__ __launch_bounds__(256) void frag_pack(
        const float* __restrict__ G, __hip_bfloat16* __restrict__ dst, int ldi) {
    constexpr int LOGN = (N == 512) ? 9 : 6;
    __shared__ __hip_bfloat16 sT[32 * (N + 8)];
    const int kc = blockIdx.x, j = blockIdx.y, c = blockIdx.z;
    const float* Gp = G + (size_t)c * 512 * ldi;
    __hip_bfloat16* db = dst + (size_t)c * 5120 * N + (size_t)(j * 16 + kc) * 32 * N;
    #pragma unroll
    for (int e = 0; e < N / 32; ++e) {
        const int idx = (e * 256 + threadIdx.x) * 4;
        const int row = idx >> LOGN, col = idx & (N - 1);
        f32x4 v = *(const f32x4*)(Gp + (size_t)(kc * 32 + row) * ldi + (size_t)j * N + col);
        __hip_bfloat16* sp = sT + row * (N + 8) + col;
        sp[0] = __float2bfloat16(tanhf(v.x));
        sp[1] = __float2bfloat16(tanhf(v.y));
        sp[2] = __float2bfloat16(tanhf(v.z));
        sp[3] = __float2bfloat16(tanhf(v.w));
    }
    __syncthreads();
    #pragma unroll
    for (int cc = 0; cc < N / 64; ++cc) {
        const int ch = cc * 256 + threadIdx.x;
        const int nt = ch >> 6, l = ch & 63;
        const int r0 = (l >> 4) * 8, cb = nt * 16 + (l & 15);
        union { __hip_bfloat16 h[8]; uint4 u; } pk;
        #pragma unroll
        for (int e = 0; e < 8; ++e) pk.h[e] = sT[(r0 + e) * (N + 8) + cb];
        *(uint4*)(db + (size_t)ch * 8) = pk.u;
    }
}

// ---------------------------------------------------------------------------
// tanh(G0) once: 5120 elems.
// ---------------------------------------------------------------------------
__global__ __launch_bounds__(512) void tanh_g0(
        const float* __restrict__ G0, float* __restrict__ tG0) {
    const int i = blockIdx.x * 512 + threadIdx.x;
    tG0[i] = tanhf(G0[i]);
}

// ---------------------------------------------------------------------------
// First core: res0[b,r] = Horner_j( tG0[j,r]; z[b,0] ) -> bf16
// ---------------------------------------------------------------------------
__global__ __launch_bounds__(512) void tt_first(
        const float* __restrict__ z, const float* __restrict__ tG0,
        __hip_bfloat16* __restrict__ res0) {
    const int r = threadIdx.x;
    const int b0 = blockIdx.x * 32;
    float tg[10];
    #pragma unroll
    for (int j = 0; j < 10; ++j) tg[j] = tG0[j * RR + r];
    #pragma unroll 1
    for (int b = 0; b < 32; ++b) {
        const float z0 = z[(size_t)(b0 + b) * DD];
        float acc = tg[9];
        #pragma unroll
        for (int j = 8; j >= 0; --j) acc = acc * z0 + tg[j];
        res0[(size_t)(b0 + b) * RR + r] = __float2bfloat16(acc);
    }
}

// ---------------------------------------------------------------------------
// Horner GEMM, K split across waves, B via depth-3 register prefetch ring,
// XCD-PINNED B-column.
//   MID (MT=4, NTOT=32): grid 1024 1-D, nb = bid & 7, m = (bid >> 3)*64.
//     Round-robin dispatch puts all blocks with a given nb on one XCD, so
//     that XCD's 640 KB B-column stays L2-resident -> every B-load ~200cyc,
//     fully covered by the ~930cyc ring gap. (Wrong mapping => neutral.)
//   LAST (MT=2, NTOT=4): grid 256 1-D, nb = 0, m = bid*32, f32 out.
//   Wave w owns K-slice [w*128, w*128+128) per j-panel; A resident in
//   MT*4 bf16x8 VGPRs; Horner over j=9..0; LDS tree-sum of 4 K-partials.
//   All fragment arrays compile-time indexed (dynamic -> scratch, r4 lesson).
// ---------------------------------------------------------------------------
template <bool LASTV, int NTOT, int MT>
__global__ __launch_bounds__(256, 2) void tt_gemm_ks(
        const __hip_bfloat16* __restrict__ resin,   // [8192][512] bf16
        const __hip_bfloat16* __restrict__ tBf,     // fragment-packed
        void* __restrict__ outp,
        const float* __restrict__ z, int d) {
    __shared__ f32x4 red[2][MT * 4][64];

    const int tid  = threadIdx.x;
    const int lane = tid & 63;
    const int wave = tid >> 6;
    const int m0 = LASTV ? blockIdx.x * (MT * 16) : (blockIdx.x >> 3) * 64;
    const int nb = LASTV ? 0 : (blockIdx.x & 7);
    const int r16 = lane & 15, quad = lane >> 4;

    // ---- A resident: a[ms*4 + s], rows m0+ms*16+r16, k = wave*128+s*32+quad*8
    bf16x8 a[MT * 4];
    #pragma unroll
    for (int ms = 0; ms < MT; ++ms)
        #pragma unroll
        for (int kst = 0; kst < 4; ++kst)
            a[ms * 4 + kst] = *(const bf16x8*)(
                resin + (size_t)(m0 + ms * 16 + r16) * RR + wave * 128 + kst * 32 + quad * 8);

    // ---- Horner row scales (C/D rows: ms*16 + quad*4 + r) ----
    float zr[MT * 4];
    #pragma unroll
    for (int ms = 0; ms < MT; ++ms)
        #pragma unroll
        for (int r = 0; r < 4; ++r)
            zr[ms * 4 + r] = z[(size_t)(m0 + ms * 16 + quad * 4 + r) * DD + d];

    f32x4 acc[MT][4];
    #pragma unroll
    for (int ms = 0; ms < MT; ++ms)
        #pragma unroll
        for (int sn = 0; sn < 4; ++sn) acc[ms][sn] = f32x4{0.f, 0.f, 0.f, 0.f};

    constexpr size_t SK = (size_t)NTOT * 512;   // elems per kc step
    constexpr size_t PJ = 16 * SK;              // elems per j panel
    const __hip_bfloat16* pB = tBf + (size_t)nb * 4 * 512
                             + (size_t)wave * 4 * SK + (size_t)lane * 8;

    // ---- 4-slot ring; preload steps 0,1,2 of panel j=9 ----
    bf16x8 bv[4][4];
    #pragma unroll
    for (int s = 0; s < 3; ++s)
        #pragma unroll
        for (int sn = 0; sn < 4; ++sn)
            bv[s][sn] = *(const bf16x8*)(pB + (size_t)9 * PJ + (size_t)s * SK + sn * 512);

#define MFMA_STEP(SLOT)                                                        \
    _Pragma("unroll")                                                          \
    for (int ms = 0; ms < MT; ++ms)                                            \
        _Pragma("unroll")                                                      \
        for (int sn = 0; sn < 4; ++sn)                                         \
            acc[ms][sn] = __builtin_amdgcn_mfma_f32_16x16x32_bf16(             \
                a[ms * 4 + SLOT], bv[SLOT][sn], acc[ms][sn], 0, 0, 0);

    #pragma unroll 1
    for (int p = 0; p < 10; ++p) {
        const int j = 9 - p;
        if (p) {
            #pragma unroll
            for (int ms = 0; ms < MT; ++ms)
                #pragma unroll
                for (int sn = 0; sn < 4; ++sn)
                    #pragma unroll
                    for (int r = 0; r < 4; ++r)
                        acc[ms][sn][r] *= zr[ms * 4 + r];
        }
        const size_t jb = (size_t)j * PJ;
        #pragma unroll
        for (int sn = 0; sn < 4; ++sn)
            bv[3][sn] = *(const bf16x8*)(pB + jb + (size_t)3 * SK + sn * 512);
        MFMA_STEP(0)
        if (p < 9) {
            #pragma unroll
            for (int sn = 0; sn < 4; ++sn)
                bv[0][sn] = *(const bf16x8*)(pB + jb - PJ + sn * 512);
        }
        MFMA_STEP(1)
        if (p < 9) {
            #pragma unroll
            for (int sn = 0; sn < 4; ++sn)
                bv[1][sn] = *(const bf16x8*)(pB + jb - PJ + SK + sn * 512);
        }
        MFMA_STEP(2)
        if (p < 9) {
            #pragma unroll
            for (int sn = 0; sn < 4; ++sn)
                bv[2][sn] = *(const bf16x8*)(pB + jb - PJ + 2 * SK + sn * 512);
        }
        MFMA_STEP(3)
    }
#undef MFMA_STEP

    // ---- cross-wave K reduction (tree identical for both variants) ----
    if (wave & 1) {
        const int idx = wave >> 1;
        #pragma unroll
        for (int i = 0; i < MT * 4; ++i) red[idx][i][lane] = acc[i >> 2][i & 3];
    }
    __syncthreads();
    if (wave == 0) {
        #pragma unroll
        for (int i = 0; i < MT * 4; ++i) acc[i >> 2][i & 3] += red[0][i][lane];
    }
    if (wave == 2) {
        #pragma unroll
        for (int i = 0; i < MT * 4; ++i) {
            f32x4 t = acc[i >> 2][i & 3] + red[1][i][lane];
            red[1][i][lane] = t;
        }
    }
    __syncthreads();
    float* rc = (float*)&red[0][0][0];   // region0 as [MT*16][64] row-major
    if (wave == 0) {
        #pragma unroll
        for (int i = 0; i < MT * 4; ++i) acc[i >> 2][i & 3] += red[1][i][lane];
        #pragma unroll
        for (int ms = 0; ms < MT; ++ms)
            #pragma unroll
            for (int sn = 0; sn < 4; ++sn)
                #pragma unroll
                for (int r = 0; r < 4; ++r)
                    rc[(ms * 16 + quad * 4 + r) * 64 + sn * 16 + r16] = acc[ms][sn][r];
    }
    __syncthreads();

    // ---- coalesced store ----
    if (LASTV) {
        // MT=2: 32 rows x 64 cols f32; thread -> (row = tid>>3, 8 cols)
        float* o = (float*)outp;
        const int row = tid >> 3, cg = (tid & 7) * 8;
        #pragma unroll
        for (int q = 0; q < 2; ++q)
            *(f32x4*)(o + (size_t)(m0 + row) * OUTD + cg + q * 4) =
                *(const f32x4*)(rc + row * 64 + cg + q * 4);
    } else {
        // MT=4: 64 rows x 64 cols bf16; thread -> (row = tid>>2, 16 cols)
        __hip_bfloat16* o = (__hip_bfloat16*)outp;
        const int row = tid >> 2, cg = (tid & 3) * 16;
        #pragma unroll
        for (int h = 0; h < 2; ++h) {
            union { __hip_bfloat16 hh[8]; uint4 u; } pk;
            #pragma unroll
            for (int e = 0; e < 8; ++e)
                pk.hh[e] = __float2bfloat16(rc[row * 64 + cg + h * 8 + e]);
            *(uint4*)(o + (size_t)(m0 + row) * RR + nb * 64 + cg + h * 8) = pk.u;
        }
    }
}

// ---------------------------------------------------------------------------
extern "C" void kernel_launch(void* const* d_in, const int* in_sizes, int n_in,
                              void* d_out, int out_size, void* d_ws, size_t ws_size,
                              hipStream_t stream) {
    const float* z     = (const float*)d_in[0];
    const float* G0    = (const float*)d_in[1];
    const float* Gmid  = (const float*)d_in[2];
    const float* Glast = (const float*)d_in[3];
    float* out = (float*)d_out;

    char* ws = (char*)d_ws;
    __hip_bfloat16* resX   = (__hip_bfloat16*)ws;                        // 8 MB
    __hip_bfloat16* resY   = (__hip_bfloat16*)(ws + ((size_t)8 << 20));  // 8 MB
    __hip_bfloat16* tBf    = (__hip_bfloat16*)(ws + ((size_t)16 << 20)); // 30 MB frag-packed mid
    __hip_bfloat16* tBlf   = (__hip_bfloat16*)(ws + ((size_t)48 << 20)); // 640 KB frag-packed last
    float* tG0             = (float*)(ws + ((size_t)52 << 20));          // 20 KB tanh(G0)

    frag_pack<512><<<dim3(16, 10, 6), 256, 0, stream>>>(Gmid,  tBf,  PP * RR);
    frag_pack<64> <<<dim3(16, 10, 1), 256, 0, stream>>>(Glast, tBlf, PP * OUTD);
    tanh_g0<<<dim3(10), 512, 0, stream>>>(G0, tG0);
    tt_first<<<dim3(BB / 32), 512, 0, stream>>>(z, tG0, resX);

    __hip_bfloat16* rin = resX;
    __hip_bfloat16* rnext = resY;
    for (int c = 0; c < 6; ++c) {
        tt_gemm_ks<false, 32, 4><<<dim3(1024), 256, 0, stream>>>(
            rin, tBf + (size_t)c * RR * KK, rnext, z, c + 1);
        __hip_bfloat16* t = rin; rin = rnext; rnext = t;
    }
    tt_gemm_ks<true, 4, 2><<<dim3(BB / 32), 256, 0, stream>>>(
        rin, tBlf, out, z, 7);
}